// Round 4
// baseline (143.832 us; speedup 1.0000x reference)
//
#include <hip/hip_runtime.h>
#include <hip/hip_bf16.h>

#define NB   64
#define NREG 4
#define ND   768
#define NH   37
#define NW   37
#define NC   5                      // 1 + NREG cues
#define NP   (NH * NW)              // 1369
#define BPB  16                     // blocks per batch -> 1024 blocks = 4/CU
#define PPB  ((NP + BPB - 1) / BPB) // 86 patches per block
#define NWAVE 4
#define KEYS_PER_BC (BPB * NWAVE)   // 64 partial keys per (b, cue)

// Map float -> unsigned int preserving order (total order, -inf .. +inf)
__device__ __forceinline__ unsigned int ord_of(float f) {
    unsigned int u = __float_as_uint(f);
    return (u & 0x80000000u) ? ~u : (u | 0x80000000u);
}

__global__ __launch_bounds__(256, 4) void fused_encoder_kernel(
    const float* __restrict__ cls_tok,
    const float* __restrict__ regs,
    const float* __restrict__ patches,
    const int* __restrict__ roi_side_p,
    float* __restrict__ out,
    unsigned long long* __restrict__ pkeys,
    unsigned int* __restrict__ cnt)
{
    const int b    = blockIdx.x / BPB;
    const int pb   = blockIdx.x % BPB;
    const int wave = threadIdx.x >> 6;
    const int lane = threadIdx.x & 63;
    const int tid  = threadIdx.x;

    // ---------------- Phase 1: sim + per-wave argmax over this block's patches
    float4 cue[NC][3];
    #pragma unroll
    for (int c = 0; c < NC; ++c) {
        const float* cb = (c == 0) ? (cls_tok + (size_t)b * ND)
                                   : (regs + ((size_t)b * NREG + (c - 1)) * ND);
        #pragma unroll
        for (int k = 0; k < 3; ++k)
            cue[c][k] = *reinterpret_cast<const float4*>(cb + k * 256 + lane * 4);
    }

    float best[NC];
    int   bidx[NC];
    #pragma unroll
    for (int c = 0; c < NC; ++c) { best[c] = -3.4e38f; bidx[c] = 0; }

    const int pstart = pb * PPB;
    const int p1     = min(NP, pstart + PPB);

    int p = pstart + wave;
    {
        const float* base = patches + ((size_t)b * NP + p) * ND + lane * 4;
        float4 v0 = *reinterpret_cast<const float4*>(base);
        float4 v1 = *reinterpret_cast<const float4*>(base + 256);
        float4 v2 = *reinterpret_cast<const float4*>(base + 512);

        while (true) {
            const int pn = p + NWAVE;
            const bool more = pn < p1;
            float4 n0, n1, n2;
            if (more) {  // issue next patch's loads before the reduce chain
                const float* nb = patches + ((size_t)b * NP + pn) * ND + lane * 4;
                n0 = *reinterpret_cast<const float4*>(nb);
                n1 = *reinterpret_cast<const float4*>(nb + 256);
                n2 = *reinterpret_cast<const float4*>(nb + 512);
            }

            float s[NC] = {0.f, 0.f, 0.f, 0.f, 0.f};
            #pragma unroll
            for (int c = 0; c < NC; ++c) {
                s[c] += v0.x * cue[c][0].x + v0.y * cue[c][0].y
                      + v0.z * cue[c][0].z + v0.w * cue[c][0].w;
                s[c] += v1.x * cue[c][1].x + v1.y * cue[c][1].y
                      + v1.z * cue[c][1].z + v1.w * cue[c][1].w;
                s[c] += v2.x * cue[c][2].x + v2.y * cue[c][2].y
                      + v2.z * cue[c][2].z + v2.w * cue[c][2].w;
            }
            #pragma unroll
            for (int c = 0; c < NC; ++c) {
                #pragma unroll
                for (int off = 32; off > 0; off >>= 1)
                    s[c] += __shfl_xor(s[c], off, 64);
                if (s[c] > best[c]) { best[c] = s[c]; bidx[c] = p; }
            }

            if (!more) break;
            v0 = n0; v1 = n1; v2 = n2; p = pn;
        }
    }

    // Publish per-wave partial keys with device-scope atomics (coherent point).
    if (lane == 0) {
        #pragma unroll
        for (int c = 0; c < NC; ++c) {
            unsigned long long key =
                ((unsigned long long)ord_of(best[c]) << 32) |
                (unsigned long long)(unsigned)(NP - 1 - bidx[c]);  // low idx wins ties
            atomicExch(&pkeys[(size_t)(b * NC + c) * KEYS_PER_BC + pb * NWAVE + wave], key);
        }
    }

    // ---------------- Arrival: LAST (16th) block of this batch does phase 2.
    // cnt[] is zeroed by hipMemsetAsync each call, so old==15 <=> last arriver.
    __syncthreads();
    __shared__ int winner_flag;
    if (tid == 0) {
        __threadfence();
        unsigned int old = atomicAdd(&cnt[b], 1u);
        winner_flag = (old == BPB - 1) ? 1 : 0;
    }
    __syncthreads();
    if (!winner_flag) return;

    __threadfence();  // acquire side

    // ---------------- Reduce partial keys with device-scope atomic READS.
    // Wave (c & 3) reduces cue c's 64 slots; cue 4 reuses wave 0.
    __shared__ unsigned long long final_key[NC];
    #pragma unroll
    for (int c = 0; c < NC; ++c) {
        if (wave == (c & 3) && (c < 4 || wave == 0)) {
            // each lane atomically reads one slot (coherent point, no stale L2)
            unsigned long long k =
                atomicAdd((unsigned long long*)&pkeys[(size_t)(b * NC + c) * KEYS_PER_BC + lane], 0ull);
            #pragma unroll
            for (int off = 32; off > 0; off >>= 1) {
                unsigned long long o = __shfl_xor(k, off, 64);
                k = max(k, o);
            }
            if (lane == 0) final_key[c] = k;
        }
    }
    __syncthreads();

    // ---------------- Phase 2: ROI mean + normalize, all 5 cues of batch b.
    const int r = roi_side_p[0] >> 1;
    __shared__ float red_x[NWAVE], red_y[NWAVE];

    for (int c = 0; c < NC; ++c) {
        const unsigned long long key = final_key[c];
        const int idx = NP - 1 - (int)(key & 0xFFFFFFFFu);
        const int hh = idx / NW, ww = idx % NW;
        const int h0 = max(0, hh - r), h1 = min(NH - 1, hh + r);
        const int w0 = max(0, ww - r), w1 = min(NW - 1, ww + r);
        const float inv_cnt = 1.0f / (float)((h1 - h0 + 1) * (w1 - w0 + 1));

        float a0 = 0.f, a1 = 0.f, a2 = 0.f;
        for (int h = h0; h <= h1; ++h) {
            for (int w = w0; w <= w1; ++w) {
                const float* pp = patches + ((size_t)b * NP + h * NW + w) * ND;
                a0 += pp[tid];
                a1 += pp[tid + 256];
                a2 += pp[tid + 512];
            }
        }
        a0 *= inv_cnt; a1 *= inv_cnt; a2 *= inv_cnt;

        const float* cb = (c == 0) ? (cls_tok + (size_t)b * ND)
                                   : (regs + ((size_t)b * NREG + (c - 1)) * ND);
        const float v0 = cb[tid], v1 = cb[tid + 256], v2 = cb[tid + 512];

        float sx = v0 * v0 + v1 * v1 + v2 * v2;
        float sy = a0 * a0 + a1 * a1 + a2 * a2;
        #pragma unroll
        for (int off = 32; off > 0; off >>= 1) {
            sx += __shfl_xor(sx, off, 64);
            sy += __shfl_xor(sy, off, 64);
        }
        if (lane == 0) { red_x[wave] = sx; red_y[wave] = sy; }
        __syncthreads();
        const float tot_x = red_x[0] + red_x[1] + red_x[2] + red_x[3];
        const float tot_y = red_y[0] + red_y[1] + red_y[2] + red_y[3];
        const float inv_nc = 1.0f / fmaxf(sqrtf(tot_x), 1e-12f);
        const float inv_nr = 1.0f / fmaxf(sqrtf(tot_y), 1e-12f);

        float* oc = out + ((size_t)b * 2 * NC + c) * ND;       // cue token
        float* om = out + ((size_t)b * 2 * NC + NC + c) * ND;  // roi token
        oc[tid]       = v0 * inv_nc;
        oc[tid + 256] = v1 * inv_nc;
        oc[tid + 512] = v2 * inv_nc;
        om[tid]       = a0 * inv_nr;
        om[tid + 256] = a1 * inv_nr;
        om[tid + 512] = a2 * inv_nr;
        __syncthreads();  // before red_x/red_y reuse
    }
}

extern "C" void kernel_launch(void* const* d_in, const int* in_sizes, int n_in,
                              void* d_out, int out_size, void* d_ws, size_t ws_size,
                              hipStream_t stream) {
    const float* cls_tok = (const float*)d_in[0];
    const float* regs    = (const float*)d_in[1];
    const float* patches = (const float*)d_in[2];
    const int*   roi     = (const int*)d_in[3];
    float* out = (float*)d_out;

    unsigned long long* pkeys = (unsigned long long*)d_ws;
    unsigned int* cnt = (unsigned int*)((char*)d_ws +
                         (size_t)NB * NC * KEYS_PER_BC * sizeof(unsigned long long));

    // Known counter start every call (harness poisons ws once, never restores).
    hipMemsetAsync(cnt, 0, NB * sizeof(unsigned int), stream);

    fused_encoder_kernel<<<NB * BPB, 256, 0, stream>>>(
        cls_tok, regs, patches, roi, out, pkeys, cnt);
}

// Round 5
// 57.174 us; speedup vs baseline: 2.5157x; 2.5157x over previous
//
#include <hip/hip_runtime.h>
#include <hip/hip_bf16.h>

#define NB   64
#define NREG 4
#define ND   768
#define NH   37
#define NW   37
#define NC   5                      // 1 + NREG cues
#define NP   (NH * NW)              // 1369
#define BPB  16                     // blocks per batch -> 1024 blocks = 4/CU
#define PPB  ((NP + BPB - 1) / BPB) // 86 patches per block
#define NWAVE 4

// Map float -> unsigned int preserving order (total order, -inf .. +inf)
__device__ __forceinline__ unsigned int ord_of(float f) {
    unsigned int u = __float_as_uint(f);
    return (u & 0x80000000u) ? ~u : (u | 0x80000000u);
}

// DPP-based wave64 sum: 6 full-rate VALU steps, no LDS ops, no lgkm waits.
// Result is the full 64-lane sum in LANE 63 (other lanes hold partials).
template <int CTRL>
__device__ __forceinline__ float dpp_add_step(float x) {
    int y = __builtin_amdgcn_update_dpp(0, __float_as_int(x), CTRL, 0xf, 0xf, true);
    return x + __int_as_float(y);
}
__device__ __forceinline__ float wave_sum_lane63(float x) {
    x = dpp_add_step<0x111>(x);  // row_shr:1
    x = dpp_add_step<0x112>(x);  // row_shr:2
    x = dpp_add_step<0x114>(x);  // row_shr:4
    x = dpp_add_step<0x118>(x);  // row_shr:8
    x = dpp_add_step<0x142>(x);  // row_bcast:15
    x = dpp_add_step<0x143>(x);  // row_bcast:31
    return x;                    // lane 63 = total
}

__global__ __launch_bounds__(256, 4) void sim_argmax_kernel(
    const float* __restrict__ cls_tok,
    const float* __restrict__ regs,
    const float* __restrict__ patches,
    unsigned long long* __restrict__ pkeys)
{
    const int b    = blockIdx.x / BPB;
    const int pb   = blockIdx.x % BPB;
    const int wave = threadIdx.x >> 6;
    const int lane = threadIdx.x & 63;

    // Preload this lane's slice of all 5 cues into registers (15 float4).
    float4 cue[NC][3];
    #pragma unroll
    for (int c = 0; c < NC; ++c) {
        const float* cb = (c == 0) ? (cls_tok + (size_t)b * ND)
                                   : (regs + ((size_t)b * NREG + (c - 1)) * ND);
        #pragma unroll
        for (int k = 0; k < 3; ++k)
            cue[c][k] = *reinterpret_cast<const float4*>(cb + k * 256 + lane * 4);
    }

    float best[NC];
    int   bidx[NC];
    #pragma unroll
    for (int c = 0; c < NC; ++c) { best[c] = -3.4e38f; bidx[c] = 0; }

    const int pstart = pb * PPB;
    const int p1     = min(NP, pstart + PPB);
    const size_t bb  = (size_t)b * NP;

    // 2-slot software pipeline: each slot's loads issue one full iteration
    // (FMAs + DPP reduce of the other slot) before their use.
    float4 A0, A1, A2, B0, B1, B2;
    int p = pstart + wave;
    {
        const float* a = patches + (bb + p) * ND + lane * 4;
        A0 = *reinterpret_cast<const float4*>(a);
        A1 = *reinterpret_cast<const float4*>(a + 256);
        A2 = *reinterpret_cast<const float4*>(a + 512);
    }
    if (p + NWAVE < p1) {
        const float* q = patches + (bb + p + NWAVE) * ND + lane * 4;
        B0 = *reinterpret_cast<const float4*>(q);
        B1 = *reinterpret_cast<const float4*>(q + 256);
        B2 = *reinterpret_cast<const float4*>(q + 512);
    } else {
        B0 = B1 = B2 = make_float4(0.f, 0.f, 0.f, 0.f);
    }

    while (true) {
        // ---- body A: current patch p (in A), prefetch A <- p + 8
        {
            float s[NC];
            #pragma unroll
            for (int c = 0; c < NC; ++c) {
                s[c] = A0.x * cue[c][0].x + A0.y * cue[c][0].y
                     + A0.z * cue[c][0].z + A0.w * cue[c][0].w
                     + A1.x * cue[c][1].x + A1.y * cue[c][1].y
                     + A1.z * cue[c][1].z + A1.w * cue[c][1].w
                     + A2.x * cue[c][2].x + A2.y * cue[c][2].y
                     + A2.z * cue[c][2].z + A2.w * cue[c][2].w;
            }
            const int pf = p + 2 * NWAVE;
            if (pf < p1) {
                const float* a = patches + (bb + pf) * ND + lane * 4;
                A0 = *reinterpret_cast<const float4*>(a);
                A1 = *reinterpret_cast<const float4*>(a + 256);
                A2 = *reinterpret_cast<const float4*>(a + 512);
            }
            #pragma unroll
            for (int c = 0; c < NC; ++c) {
                float t = wave_sum_lane63(s[c]);
                if (t > best[c]) { best[c] = t; bidx[c] = p; }
            }
        }
        p += NWAVE;
        if (p >= p1) break;

        // ---- body B: current patch p (in B), prefetch B <- p + 8
        {
            float s[NC];
            #pragma unroll
            for (int c = 0; c < NC; ++c) {
                s[c] = B0.x * cue[c][0].x + B0.y * cue[c][0].y
                     + B0.z * cue[c][0].z + B0.w * cue[c][0].w
                     + B1.x * cue[c][1].x + B1.y * cue[c][1].y
                     + B1.z * cue[c][1].z + B1.w * cue[c][1].w
                     + B2.x * cue[c][2].x + B2.y * cue[c][2].y
                     + B2.z * cue[c][2].z + B2.w * cue[c][2].w;
            }
            const int pf = p + 2 * NWAVE;
            if (pf < p1) {
                const float* q = patches + (bb + pf) * ND + lane * 4;
                B0 = *reinterpret_cast<const float4*>(q);
                B1 = *reinterpret_cast<const float4*>(q + 256);
                B2 = *reinterpret_cast<const float4*>(q + 512);
            }
            #pragma unroll
            for (int c = 0; c < NC; ++c) {
                float t = wave_sum_lane63(s[c]);
                if (t > best[c]) { best[c] = t; bidx[c] = p; }
            }
        }
        p += NWAVE;
        if (p >= p1) break;
    }

    // Combine the 4 waves' bests in LDS, then one plain store per cue.
    __shared__ unsigned long long lk[NWAVE][NC];
    if (lane == 63) {  // DPP sum lives in lane 63
        #pragma unroll
        for (int c = 0; c < NC; ++c) {
            lk[wave][c] =
                ((unsigned long long)ord_of(best[c]) << 32) |
                (unsigned long long)(unsigned)(NP - 1 - bidx[c]);  // low idx wins ties
        }
    }
    __syncthreads();
    if (threadIdx.x < NC) {
        unsigned long long k = lk[0][threadIdx.x];
        k = max(k, lk[1][threadIdx.x]);
        k = max(k, lk[2][threadIdx.x]);
        k = max(k, lk[3][threadIdx.x]);
        pkeys[(b * NC + threadIdx.x) * BPB + pb] = k;
    }
}

// One block per (b, cue): reduce partial keys, clipped-window mean,
// normalize cue & roi tokens.
__global__ __launch_bounds__(256) void roi_norm_kernel(
    const float* __restrict__ cls_tok,
    const float* __restrict__ regs,
    const float* __restrict__ patches,
    const unsigned long long* __restrict__ pkeys,
    const int* __restrict__ roi_side_p,
    float* __restrict__ out)
{
    const int b   = blockIdx.x / NC;
    const int c   = blockIdx.x % NC;
    const int tid = threadIdx.x;
    const int wave = tid >> 6, lane = tid & 63;
    const int r = roi_side_p[0] >> 1;

    // All threads redundantly reduce the BPB partial keys (uniform loads).
    const unsigned long long* pk = pkeys + (b * NC + c) * BPB;
    unsigned long long key = pk[0];
    #pragma unroll
    for (int i = 1; i < BPB; ++i) key = max(key, pk[i]);

    const int idx = NP - 1 - (int)(key & 0xFFFFFFFFu);
    const int hh = idx / NW, ww = idx % NW;
    const int h0 = max(0, hh - r), h1 = min(NH - 1, hh + r);
    const int w0 = max(0, ww - r), w1 = min(NW - 1, ww + r);
    const float inv_cnt = 1.0f / (float)((h1 - h0 + 1) * (w1 - w0 + 1));

    float a0 = 0.f, a1 = 0.f, a2 = 0.f;
    for (int h = h0; h <= h1; ++h) {
        for (int w = w0; w <= w1; ++w) {
            const float* p = patches + ((size_t)b * NP + h * NW + w) * ND;
            a0 += p[tid];
            a1 += p[tid + 256];
            a2 += p[tid + 512];
        }
    }
    a0 *= inv_cnt; a1 *= inv_cnt; a2 *= inv_cnt;

    const float* cb = (c == 0) ? (cls_tok + (size_t)b * ND)
                               : (regs + ((size_t)b * NREG + (c - 1)) * ND);
    const float v0 = cb[tid], v1 = cb[tid + 256], v2 = cb[tid + 512];

    // Block-reduce two sums of squares (cue, roi).
    float sx = v0 * v0 + v1 * v1 + v2 * v2;
    float sy = a0 * a0 + a1 * a1 + a2 * a2;
    #pragma unroll
    for (int off = 32; off > 0; off >>= 1) {
        sx += __shfl_xor(sx, off, 64);
        sy += __shfl_xor(sy, off, 64);
    }
    __shared__ float red_x[4], red_y[4];
    if (lane == 0) { red_x[wave] = sx; red_y[wave] = sy; }
    __syncthreads();
    const float tot_x = red_x[0] + red_x[1] + red_x[2] + red_x[3];
    const float tot_y = red_y[0] + red_y[1] + red_y[2] + red_y[3];
    const float inv_nc = 1.0f / fmaxf(sqrtf(tot_x), 1e-12f);
    const float inv_nr = 1.0f / fmaxf(sqrtf(tot_y), 1e-12f);

    float* oc = out + ((size_t)b * 2 * NC + c) * ND;       // cue token
    float* om = out + ((size_t)b * 2 * NC + NC + c) * ND;  // roi token
    oc[tid]       = v0 * inv_nc;
    oc[tid + 256] = v1 * inv_nc;
    oc[tid + 512] = v2 * inv_nc;
    om[tid]       = a0 * inv_nr;
    om[tid + 256] = a1 * inv_nr;
    om[tid + 512] = a2 * inv_nr;
}

extern "C" void kernel_launch(void* const* d_in, const int* in_sizes, int n_in,
                              void* d_out, int out_size, void* d_ws, size_t ws_size,
                              hipStream_t stream) {
    const float* cls_tok = (const float*)d_in[0];
    const float* regs    = (const float*)d_in[1];
    const float* patches = (const float*)d_in[2];
    const int*   roi     = (const int*)d_in[3];
    float* out = (float*)d_out;
    unsigned long long* pkeys = (unsigned long long*)d_ws;

    sim_argmax_kernel<<<NB * BPB, 256, 0, stream>>>(cls_tok, regs, patches, pkeys);
    roi_norm_kernel<<<NB * NC, 256, 0, stream>>>(cls_tok, regs, patches, pkeys, roi, out);
}